// Round 6
// baseline (138.758 us; speedup 1.0000x reference)
//
#include <hip/hip_runtime.h>
#include <cstdint>
#include <cstddef>

#define DIMC    192
#define NHEADS  6
#define NATT    486
#define NB      16
#define NH      56
#define NWW     56
#define HPOOL   28
#define WPOOL   28
#define NPIX    784
#define VH      58
#define VW      58
#define MROWS   (NB*NH*NWW)      // 50176
#define MPOOL   (NB*NPIX)        // 12544
#define SCALE_A 0.17677669529663687f

using bf16x8 = __attribute__((ext_vector_type(8))) short;
using f32x4  = __attribute__((ext_vector_type(4))) float;

static __device__ __forceinline__ unsigned short f2bf(float f) {
    unsigned int u = __float_as_uint(f);
    unsigned int r = (u + 0x7fffu + ((u >> 16) & 1u)) >> 16;   // RNE
    return (unsigned short)r;
}
static __device__ __forceinline__ float bf2f(unsigned short u) {
    return __uint_as_float((unsigned int)u << 16);
}

// =====================================================================
// Weight prep: WTv/WTp[n][k] = bf16(W[k][n]); WaT[512][192] = bf16(Wa[k][n]*SCALE)
// =====================================================================
__global__ __launch_bounds__(256)
void wt_convert_kernel(const float* __restrict__ Wv, const float* __restrict__ Wp,
                       const float* __restrict__ Wa,
                       unsigned short* __restrict__ WTv, unsigned short* __restrict__ WTp,
                       unsigned short* __restrict__ WaT)
{
    int idx = blockIdx.x * 256 + threadIdx.x;        // 0..172031
    if (idx < 73728) {
        int sel = idx / 36864;
        int r   = idx - sel * 36864;
        int n   = r / DIMC;
        int k   = r - n * DIMC;
        const float* W = sel ? Wp : Wv;
        unsigned short* WT = sel ? WTp : WTv;
        WT[r] = f2bf(W[k * DIMC + n]);
    } else {
        int r = idx - 73728;                          // 0..98303
        int n = r / DIMC;
        int k = r - n * DIMC;
        WaT[r] = (n < NATT) ? f2bf(Wa[(size_t)k * NATT + n] * SCALE_A) : (unsigned short)0;
    }
}

// =====================================================================
// Zero the 1-pixel border of vp (bf16), as uint writes
// =====================================================================
__global__ __launch_bounds__(256)
void vp_border_zero_kernel(unsigned int* __restrict__ vpu)
{
    int idx = blockIdx.x * 256 + threadIdx.x;
    if (idx >= 350208) return;
    int cu   = idx % 96;
    int rest = idx / 96;
    int b    = rest / 228;
    int p    = rest - b * 228;
    int hi, wi;
    if (p < 58)       { hi = 0;  wi = p; }
    else if (p < 116) { hi = 57; wi = p - 58; }
    else { int q = p - 116; hi = 1 + (q >> 1); wi = (q & 1) * 57; }
    vpu[(((size_t)b * VH + hi) * VW + wi) * 96 + cu] = 0u;
}

// =====================================================================
// MFMA GEMM, BM=64, BN=192 (full), 4 waves (2x2).
// MODE 0: A fp32 (x), C bf16 scattered into padded vp
// MODE 1: A bf16 (y), C fp32 + bias -> out
// =====================================================================
template<int MODE>
__global__ __launch_bounds__(256)
void mfma_gemm_kernel(const void* __restrict__ Av, const unsigned short* __restrict__ WT,
                      const float* __restrict__ bias, void* __restrict__ Cv)
{
    __shared__ unsigned short As[64 * DIMC];   // 24 KB swizzled bf16

    const int t  = threadIdx.x;
    const int l  = t & 63;
    const int w  = t >> 6;
    const int wr = w >> 1;
    const int wc = w & 1;
    const int by = blockIdx.x;

    if (MODE == 0) {
        const float* Ab = (const float*)Av + (size_t)by * 64 * DIMC;
#pragma unroll
        for (int i = 0; i < 12; ++i) {
            int f = i * 1024 + t * 4;
            float4 v = *(const float4*)(Ab + f);
            int row = f / DIMC;
            int k   = f - row * DIMC;
            ushort4 u;
            u.x = f2bf(v.x); u.y = f2bf(v.y); u.z = f2bf(v.z); u.w = f2bf(v.w);
            int off = (row * 384 + k * 2) ^ ((row & 7) << 4);
            *(ushort4*)((char*)As + off) = u;
        }
    } else {
        const unsigned short* Ab = (const unsigned short*)Av + (size_t)by * 64 * DIMC;
#pragma unroll
        for (int i = 0; i < 6; ++i) {
            int f = i * 2048 + t * 8;
            bf16x8 v = *(const bf16x8*)(Ab + f);
            int row = f / DIMC;
            int k   = f - row * DIMC;
            int off = (row * 384 + k * 2) ^ ((row & 7) << 4);
            *(bf16x8*)((char*)As + off) = v;
        }
    }
    __syncthreads();

    f32x4 acc[2][6];
#pragma unroll
    for (int mi = 0; mi < 2; ++mi)
#pragma unroll
        for (int ni = 0; ni < 6; ++ni) acc[mi][ni] = (f32x4)0.f;

    const int arow0 = wr * 32 + (l & 15);
    const int kb    = (l >> 4) << 4;

#pragma unroll
    for (int ks = 0; ks < 6; ++ks) {
        bf16x8 a[2], b[6];
#pragma unroll
        for (int mi = 0; mi < 2; ++mi) {
            int row = arow0 + mi * 16;
            int off = (row * 384 + ks * 64 + kb) ^ ((row & 7) << 4);
            a[mi] = *(const bf16x8*)((const char*)As + off);
        }
#pragma unroll
        for (int ni = 0; ni < 6; ++ni) {
            int n = wc * 96 + ni * 16 + (l & 15);
            b[ni] = *(const bf16x8*)(WT + (size_t)n * DIMC + ks * 32 + ((l >> 4) << 3));
        }
#pragma unroll
        for (int mi = 0; mi < 2; ++mi)
#pragma unroll
            for (int ni = 0; ni < 6; ++ni)
                acc[mi][ni] = __builtin_amdgcn_mfma_f32_16x16x32_bf16(
                    a[mi], b[ni], acc[mi][ni], 0, 0, 0);
    }

#pragma unroll
    for (int mi = 0; mi < 2; ++mi) {
#pragma unroll
        for (int r = 0; r < 4; ++r) {
            int m = by * 64 + wr * 32 + mi * 16 + ((l >> 4) << 2) + r;
            if (MODE == 1) {
                float* dst = (float*)Cv + (size_t)m * DIMC;
#pragma unroll
                for (int ni = 0; ni < 6; ++ni) {
                    int col = wc * 96 + ni * 16 + (l & 15);
                    dst[col] = acc[mi][ni][r] + bias[col];
                }
            } else {
                int bb = m / (NH * NWW);
                int rr = m - bb * (NH * NWW);
                int hi = rr / NWW;
                int wi = rr - hi * NWW;
                unsigned short* dst = (unsigned short*)Cv +
                    (((size_t)bb * VH + hi + 1) * VW + (wi + 1)) * DIMC;
#pragma unroll
                for (int ni = 0; ni < 6; ++ni) {
                    int col = wc * 96 + ni * 16 + (l & 15);
                    dst[col] = f2bf(acc[mi][ni][r]);
                }
            }
        }
    }
}

// =====================================================================
// Fused pool + MFMA GEMM (M=12544, N=512pad, K=192) + softmax -> attn bf16
// =====================================================================
__global__ __launch_bounds__(512)
void pool_attn_mfma_kernel(const float* __restrict__ x, const unsigned short* __restrict__ WaT,
                           const float* __restrict__ ba, unsigned short* __restrict__ attn)
{
    __shared__ unsigned short As[64 * DIMC];   // 24 KB
    __shared__ float Cs[16][489];              // 31.3 KB chunk
    __shared__ float ba_s[NATT];

    const int t  = threadIdx.x;
    const int l  = t & 63;
    const int w  = t >> 6;
    const int wr = w >> 2;
    const int wc = w & 3;
    const int by = blockIdx.x;

    if (t < NATT) ba_s[t] = ba[t] * SCALE_A;

#pragma unroll
    for (int i = 0; i < 6; ++i) {
        int f   = i * 2048 + t * 4;
        int row = f / DIMC;
        int k   = f - row * DIMC;
        int m   = by * 64 + row;
        int b   = m / NPIX;
        int r   = m - b * NPIX;
        int hh  = r / WPOOL;
        int ww  = r - hh * WPOOL;
        const float* xp = x + (((size_t)(b * NH + hh * 2)) * NWW + ww * 2) * DIMC + k;
        float4 v0 = *(const float4*)(xp);
        float4 v1 = *(const float4*)(xp + DIMC);
        float4 v2 = *(const float4*)(xp + (size_t)NWW * DIMC);
        float4 v3 = *(const float4*)(xp + (size_t)NWW * DIMC + DIMC);
        ushort4 u;
        u.x = f2bf(0.25f * (v0.x + v1.x + v2.x + v3.x));
        u.y = f2bf(0.25f * (v0.y + v1.y + v2.y + v3.y));
        u.z = f2bf(0.25f * (v0.z + v1.z + v2.z + v3.z));
        u.w = f2bf(0.25f * (v0.w + v1.w + v2.w + v3.w));
        int off = (row * 384 + k * 2) ^ ((row & 7) << 4);
        *(ushort4*)((char*)As + off) = u;
    }
    __syncthreads();

    f32x4 acc[2][8];
#pragma unroll
    for (int mi = 0; mi < 2; ++mi)
#pragma unroll
        for (int ni = 0; ni < 8; ++ni) acc[mi][ni] = (f32x4)0.f;

    const int arow0 = wr * 32 + (l & 15);
    const int kb    = (l >> 4) << 4;

#pragma unroll
    for (int ks = 0; ks < 6; ++ks) {
        bf16x8 a[2], b[8];
#pragma unroll
        for (int mi = 0; mi < 2; ++mi) {
            int row = arow0 + mi * 16;
            int off = (row * 384 + ks * 64 + kb) ^ ((row & 7) << 4);
            a[mi] = *(const bf16x8*)((const char*)As + off);
        }
#pragma unroll
        for (int ni = 0; ni < 8; ++ni) {
            int n = wc * 128 + ni * 16 + (l & 15);
            b[ni] = *(const bf16x8*)(WaT + (size_t)n * DIMC + ks * 32 + ((l >> 4) << 3));
        }
#pragma unroll
        for (int mi = 0; mi < 2; ++mi)
#pragma unroll
            for (int ni = 0; ni < 8; ++ni)
                acc[mi][ni] = __builtin_amdgcn_mfma_f32_16x16x32_bf16(
                    a[mi], b[ni], acc[mi][ni], 0, 0, 0);
    }

#pragma unroll
    for (int r0 = 0; r0 < 64; r0 += 16) {
        const int mi = (r0 >> 4) & 1;
        if (wr == (r0 >> 5)) {
#pragma unroll
            for (int ni = 0; ni < 8; ++ni) {
                int col = wc * 128 + ni * 16 + (l & 15);
                if (col < NATT) {
#pragma unroll
                    for (int r = 0; r < 4; ++r)
                        Cs[((l >> 4) << 2) + r][col] =
                            (mi == 0 ? acc[0][ni][r] : acc[1][ni][r]) + ba_s[col];
                }
            }
        }
        __syncthreads();
        for (int g = t; g < 864; g += 512) {
            int lr = g / 54;
            int gc = (g - lr * 54) * 9;
            const float* ap = &Cs[lr][gc];
            float mx = ap[0];
#pragma unroll
            for (int q = 1; q < 9; ++q) mx = fmaxf(mx, ap[q]);
            float e[9];
            float sum = 0.f;
#pragma unroll
            for (int q = 0; q < 9; ++q) { e[q] = __expf(ap[q] - mx); sum += e[q]; }
            float inv = 1.f / sum;
            int m = by * 64 + r0 + lr;
            unsigned short* dst = attn + (size_t)m * NATT + gc;
#pragma unroll
            for (int q = 0; q < 9; ++q) dst[q] = f2bf(e[q] * inv);
        }
        __syncthreads();
    }
}

// =====================================================================
// Gather: 4 same-parity pixels per 192-thr block (48 thr/pixel, 4 ch each,
// ushort4 vp loads). Block-uniform (NI,NJ). attn/vp/y all bf16.
// Bijective XCD swizzle: 12544 = 8*1568 -> 2 whole batches per XCD.
// =====================================================================
template<int NI, int NJ>
static __device__ __forceinline__ void gather_body(
    int b, int p, int qc, int head, int c,
    const unsigned short* __restrict__ attn, const unsigned short* __restrict__ vp,
    unsigned short* __restrict__ y)
{
    const int pr = p >> 1;
    const int qr = qc >> 1;

    float acc0 = 0.f, acc1 = 0.f, acc2 = 0.f, acc3 = 0.f;

#pragma unroll
    for (int wi = 0; wi < NI; ++wi) {
        const int  hh  = pr + wi;
        const bool hv  = (NI == 1) || (wi == 0) || (pr + 1 < HPOOL);
        const int  hhs = hv ? hh : (HPOOL - 1);
        const int  iof = (NI == 1) ? 1 : (wi == 0 ? 2 : 0);
#pragma unroll
        for (int wj = 0; wj < NJ; ++wj) {
            const int  ww  = qr + wj;
            const bool wv  = (NJ == 1) || (wj == 0) || (qr + 1 < WPOOL);
            const int  wws = wv ? ww : (WPOOL - 1);
            const bool ok  = hv && wv;
            const int  jof = (NJ == 1) ? 1 : (wj == 0 ? 2 : 0);

            const unsigned short* ap = attn +
                ((size_t)(b * NPIX + hhs * WPOOL + wws) * NATT + head * 81 + (iof * 3 + jof) * 9);
            float a[9];
#pragma unroll
            for (int k = 0; k < 9; ++k) a[k] = ok ? bf2f(ap[k]) : 0.f;

            const unsigned short* vb = vp +
                (((size_t)(b * VH + 2 * hhs)) * VW + 2 * wws) * DIMC + c;
            ushort4 v[9];
#pragma unroll
            for (int qi = 0; qi < 3; ++qi)
#pragma unroll
                for (int qj = 0; qj < 3; ++qj)
                    v[qi * 3 + qj] = *(const ushort4*)(vb + ((size_t)qi * VW + qj) * DIMC);

#pragma unroll
            for (int k = 0; k < 9; ++k) {
                acc0 = fmaf(a[k], bf2f(v[k].x), acc0);
                acc1 = fmaf(a[k], bf2f(v[k].y), acc1);
                acc2 = fmaf(a[k], bf2f(v[k].z), acc2);
                acc3 = fmaf(a[k], bf2f(v[k].w), acc3);
            }
        }
    }
    size_t pix = (size_t)b * (NH * NWW) + (size_t)p * NWW + qc;
    ushort4 r;
    r.x = f2bf(acc0); r.y = f2bf(acc1); r.z = f2bf(acc2); r.w = f2bf(acc3);
    *(ushort4*)(y + pix * DIMC + c) = r;
}

__global__ __launch_bounds__(192)
void gather_kernel(const unsigned short* __restrict__ attn,
                   const unsigned short* __restrict__ vp,
                   unsigned short* __restrict__ y)
{
    const int t    = threadIdx.x;
    const int pi   = t / 48;            // pixel in block (0..3)
    const int ct   = t - pi * 48;       // channel-thread (0..47)
    const int c    = ct * 4;
    const int head = ct >> 3;

    const int flat = blockIdx.x;                       // 12544 = 8*1568
    const int wgid = (flat & 7) * 1568 + (flat >> 3);  // XCD i -> batches 2i,2i+1
    const int b    = wgid / 784;
    const int rem  = wgid - b * 784;
    const int p    = rem / 14;
    const int g    = rem - p * 14;
    const int parity = g & 1;
    const int qc   = parity + (g >> 1) * 8 + pi * 2;   // 0..55, block-uniform parity

    if (p & 1) {
        if (parity) gather_body<2, 2>(b, p, qc, head, c, attn, vp, y);
        else        gather_body<2, 1>(b, p, qc, head, c, attn, vp, y);
    } else {
        if (parity) gather_body<1, 2>(b, p, qc, head, c, attn, vp, y);
        else        gather_body<1, 1>(b, p, qc, head, c, attn, vp, y);
    }
}

// =====================================================================
extern "C" void kernel_launch(void* const* d_in, const int* in_sizes, int n_in,
                              void* d_out, int out_size, void* d_ws, size_t ws_size,
                              hipStream_t stream)
{
    const float* x  = (const float*)d_in[0];
    const float* Wv = (const float*)d_in[1];
    const float* Wa = (const float*)d_in[2];
    const float* ba = (const float*)d_in[3];
    const float* Wp = (const float*)d_in[4];
    const float* bp = (const float*)d_in[5];
    float* out = (float*)d_out;

    const size_t vp_elems   = (size_t)NB * VH * VW * DIMC;   // bf16
    const size_t attn_elems = (size_t)MPOOL * NATT;          // bf16
    const size_t y_elems    = (size_t)MROWS * DIMC;          // bf16

    unsigned short* vp   = (unsigned short*)d_ws;
    unsigned short* attn = vp + vp_elems;
    unsigned short* y    = attn + attn_elems;
    unsigned short* WTv  = y + y_elems;
    unsigned short* WTp  = WTv + 36864;
    unsigned short* WaT  = WTp + 36864;

    vp_border_zero_kernel<<<1369, 256, 0, stream>>>((unsigned int*)vp);
    wt_convert_kernel<<<672, 256, 0, stream>>>(Wv, Wp, Wa, WTv, WTp, WaT);

    mfma_gemm_kernel<0><<<MROWS / 64, 256, 0, stream>>>(x, WTv, nullptr, vp);
    pool_attn_mfma_kernel<<<MPOOL / 64, 512, 0, stream>>>(x, WaT, ba, attn);

    gather_kernel<<<12544, 192, 0, stream>>>(attn, vp, y);

    mfma_gemm_kernel<1><<<MROWS / 64, 256, 0, stream>>>(y, WTp, bp, out);
}